// Round 3
// baseline (164.916 us; speedup 1.0000x reference)
//
#include <hip/hip_runtime.h>
#include <math.h>

// Problem constants (fixed by setup_inputs): B=16, C=1, H=W=512, M=500, DIM=7
namespace {
constexpr int Bc = 16;
constexpr int Mc = 500;
constexpr int Hc = 512;
constexpr int Wc = 512;
constexpr int HWc = Hc * Wc;
constexpr int Dc = 7;
constexpr int NPAIR = Bc * Mc;              // 8000
constexpr int BLOCK = 64;                   // 1 wave/block -> 125 blocks spread over CUs
constexpr int NBLK = NPAIR / BLOCK;         // 125 exactly
}

// Append a point to a register-resident 8-slot polygon. Fully unrolled select
// chain: all array indices are compile-time constants, so the arrays stay in
// VGPRs (no scratch).
__device__ __forceinline__ void push_pt(float (&qx)[8], float (&qy)[8], int& m,
                                        float nx, float ny) {
#pragma unroll
    for (int s = 0; s < 8; ++s) {
        if (s == m) { qx[s] = nx; qy[s] = ny; }
    }
    ++m;
}

// One Sutherland-Hodgman pass: clip polygon (Px,Py,n) against half-plane
// sx*x + sy*y <= lim.
__device__ __forceinline__ void clip_pass(float (&Px)[8], float (&Py)[8], int& n,
                                          float sx, float sy, float lim) {
    float Qx[8], Qy[8];
    int m = 0;
    const int nn = n;
#pragma unroll
    for (int k = 0; k < 8; ++k) {
        if (k < nn) {
            const float cx = Px[k], cy = Py[k];
            float nx, ny;
            if (k == 7) { nx = Px[0]; ny = Py[0]; }
            else if (k + 1 == nn) { nx = Px[0]; ny = Py[0]; }
            else { nx = Px[k + 1]; ny = Py[k + 1]; }
            const float dc = lim - (sx * cx + sy * cy);  // >=0 : inside
            const float dn = lim - (sx * nx + sy * ny);
            const bool cin = dc >= 0.f;
            const bool nin = dn >= 0.f;
            if (cin) push_pt(Qx, Qy, m, cx, cy);
            if (cin != nin) {
                const float t = dc / (dc - dn);  // denom != 0 when signs differ
                push_pt(Qx, Qy, m, cx + t * (nx - cx), cy + t * (ny - cy));
            }
        }
    }
    n = m;
#pragma unroll
    for (int k = 0; k < 8; ++k) { Px[k] = Qx[k]; Py[k] = Qy[k]; }
}

// BEV intersection area of two rotated rectangles via polygon clipping in
// box-b's local frame (b becomes axis-aligned).
__device__ float bev_inter(const float* __restrict__ a, const float* __restrict__ b) {
    float sA, cA, sB, cB;
    __sincosf(a[6], &sA, &cA);
    __sincosf(b[6], &sB, &cB);
    const float cR = cA * cB + sA * sB;
    const float sR = sA * cB - cA * sB;
    const float dxw = a[0] - b[0], dyw = a[1] - b[1];
    const float ox = dxw * cB + dyw * sB;
    const float oy = -dxw * sB + dyw * cB;

    const float t0[4] = {0.5f, -0.5f, -0.5f, 0.5f};
    const float t1[4] = {0.5f, 0.5f, -0.5f, -0.5f};
    float Px[8], Py[8];
#pragma unroll
    for (int i = 0; i < 4; ++i) {
        const float lx = t0[i] * a[3], ly = t1[i] * a[4];
        Px[i] = lx * cR - ly * sR + ox;
        Py[i] = lx * sR + ly * cR + oy;
    }
#pragma unroll
    for (int i = 4; i < 8; ++i) { Px[i] = 0.f; Py[i] = 0.f; }
    int n = 4;

    const float hx = b[3] * 0.5f, hy = b[4] * 0.5f;
    clip_pass(Px, Py, n, 1.f, 0.f, hx);
    clip_pass(Px, Py, n, -1.f, 0.f, hx);
    clip_pass(Px, Py, n, 0.f, 1.f, hy);
    clip_pass(Px, Py, n, 0.f, -1.f, hy);

    float area2 = 0.f;
#pragma unroll
    for (int k = 0; k < 8; ++k) {
        if (k < n) {
            float nx, ny;
            if (k == 7) { nx = Px[0]; ny = Py[0]; }
            else if (k + 1 == n) { nx = Px[0]; ny = Py[0]; }
            else { nx = Px[k + 1]; ny = Py[k + 1]; }
            area2 += Px[k] * ny - Py[k] * nx;
        }
    }
    return 0.5f * fabsf(area2);
}

__device__ float iou3d(const float* __restrict__ a, const float* __restrict__ b) {
    const float inter_bev = bev_inter(a, b);
    const float top = fminf(a[2] + a[5] * 0.5f, b[2] + b[5] * 0.5f);
    const float bot = fmaxf(a[2] - a[5] * 0.5f, b[2] - b[5] * 0.5f);
    const float inter = inter_bev * fmaxf(top - bot, 0.f);
    const float va = a[3] * a[4] * a[5];
    const float vb = b[3] * b[4] * b[5];
    return inter / fmaxf(va + vb - inter, 1e-6f);
}

// ws layout (floats): [0]=sum_term, [1]=sum_mask, [2]=ticket (int) — zeroed
// by a 12-byte memset node each launch.
__global__ void __launch_bounds__(BLOCK)
iou_loss_fused(const float* __restrict__ iou_pred,
               const int* __restrict__ mask,
               const int* __restrict__ ind,
               const float* __restrict__ box_pred,
               const float* __restrict__ box_gt,
               float* __restrict__ ws,
               float* __restrict__ out) {
    const int idx = blockIdx.x * BLOCK + threadIdx.x;  // always < NPAIR (exact fit)
    const int b = idx / Mc;
    const int i = ind[idx];
    const float pred = iou_pred[(size_t)b * HWc + i];

    float pb[7], gb[7];
    const float* bp = box_pred + (size_t)b * Dc * HWc + i;
#pragma unroll
    for (int d = 0; d < 7; ++d) pb[d] = bp[(size_t)d * HWc];
#pragma unroll
    for (int d = 0; d < 7; ++d) gb[d] = box_gt[(size_t)idx * 7 + d];

    const float iou = iou3d(pb, gb);
    const float target = 2.f * iou - 1.f;
    const float mm = (float)mask[idx];
    float term = fabsf(pred - target) * mm;
    float mv = mm;

    // single-wave block: pure shuffle reduction
#pragma unroll
    for (int off = 32; off > 0; off >>= 1) {
        term += __shfl_down(term, off);
        mv += __shfl_down(mv, off);
    }

    int old = 0;
    if (threadIdx.x == 0) {
        atomicAdd(&ws[0], term);   // device-scope fp32 atomics (G12)
        atomicAdd(&ws[1], mv);
        __threadfence();           // release: sums visible device-wide
        old = atomicAdd((int*)&ws[2], 1);
    }
    old = __shfl(old, 0);
    if (old == NBLK - 1 && threadIdx.x == 0) {
        __threadfence();           // acquire side
        const float s = __hip_atomic_load(&ws[0], __ATOMIC_ACQUIRE, __HIP_MEMORY_SCOPE_AGENT);
        const float m = __hip_atomic_load(&ws[1], __ATOMIC_ACQUIRE, __HIP_MEMORY_SCOPE_AGENT);
        out[0] = s / (m + 1e-4f);
    }
}

extern "C" void kernel_launch(void* const* d_in, const int* in_sizes, int n_in,
                              void* d_out, int out_size, void* d_ws, size_t ws_size,
                              hipStream_t stream) {
    const float* iou_pred = (const float*)d_in[0];
    const int* mask = (const int*)d_in[1];
    const int* ind = (const int*)d_in[2];
    const float* box_pred = (const float*)d_in[3];
    const float* box_gt = (const float*)d_in[4];
    float* ws = (float*)d_ws;
    float* out = (float*)d_out;

    // zero-init the 2 accumulators + ticket counter (graph-capturable memset node)
    hipMemsetAsync(ws, 0, 12, stream);
    iou_loss_fused<<<NBLK, BLOCK, 0, stream>>>(iou_pred, mask, ind, box_pred, box_gt, ws, out);
}

// Round 4
// 163.087 us; speedup vs baseline: 1.0112x; 1.0112x over previous
//
#include <hip/hip_runtime.h>
#include <math.h>

// Problem constants (fixed by setup_inputs): B=16, C=1, H=W=512, M=500, DIM=7
namespace {
constexpr int Bc = 16;
constexpr int Mc = 500;
constexpr int Hc = 512;
constexpr int Wc = 512;
constexpr int HWc = Hc * Wc;
constexpr int Dc = 7;
constexpr int NPAIR = Bc * Mc;              // 8000
constexpr int BLOCK = 64;                   // 1 wave/block -> 125 blocks spread over CUs
constexpr int NBLK = NPAIR / BLOCK;         // 125 exactly
}

// Append a point to a register-resident 8-slot polygon. Fully unrolled select
// chain: all array indices are compile-time constants, so the arrays stay in
// VGPRs (no scratch).
__device__ __forceinline__ void push_pt(float (&qx)[8], float (&qy)[8], int& m,
                                        float nx, float ny) {
#pragma unroll
    for (int s = 0; s < 8; ++s) {
        if (s == m) { qx[s] = nx; qy[s] = ny; }
    }
    ++m;
}

// One Sutherland-Hodgman pass: clip polygon (Px,Py,n) against half-plane
// sx*x + sy*y <= lim.
__device__ __forceinline__ void clip_pass(float (&Px)[8], float (&Py)[8], int& n,
                                          float sx, float sy, float lim) {
    float Qx[8], Qy[8];
    int m = 0;
    const int nn = n;
#pragma unroll
    for (int k = 0; k < 8; ++k) {
        if (k < nn) {
            const float cx = Px[k], cy = Py[k];
            float nx, ny;
            if (k == 7) { nx = Px[0]; ny = Py[0]; }
            else if (k + 1 == nn) { nx = Px[0]; ny = Py[0]; }
            else { nx = Px[k + 1]; ny = Py[k + 1]; }
            const float dc = lim - (sx * cx + sy * cy);  // >=0 : inside
            const float dn = lim - (sx * nx + sy * ny);
            const bool cin = dc >= 0.f;
            const bool nin = dn >= 0.f;
            if (cin) push_pt(Qx, Qy, m, cx, cy);
            if (cin != nin) {
                const float t = dc / (dc - dn);  // denom != 0 when signs differ
                push_pt(Qx, Qy, m, cx + t * (nx - cx), cy + t * (ny - cy));
            }
        }
    }
    n = m;
#pragma unroll
    for (int k = 0; k < 8; ++k) { Px[k] = Qx[k]; Py[k] = Qy[k]; }
}

// BEV intersection area of two rotated rectangles via polygon clipping in
// box-b's local frame (b becomes axis-aligned). Rotation-invariant, matches
// the reference's world-frame area up to fp rounding.
__device__ float bev_inter(const float* __restrict__ a, const float* __restrict__ b) {
    float sA, cA, sB, cB;
    __sincosf(a[6], &sA, &cA);
    __sincosf(b[6], &sB, &cB);
    const float cR = cA * cB + sA * sB;
    const float sR = sA * cB - cA * sB;
    const float dxw = a[0] - b[0], dyw = a[1] - b[1];
    const float ox = dxw * cB + dyw * sB;
    const float oy = -dxw * sB + dyw * cB;

    const float t0[4] = {0.5f, -0.5f, -0.5f, 0.5f};
    const float t1[4] = {0.5f, 0.5f, -0.5f, -0.5f};
    float Px[8], Py[8];
#pragma unroll
    for (int i = 0; i < 4; ++i) {
        const float lx = t0[i] * a[3], ly = t1[i] * a[4];
        Px[i] = lx * cR - ly * sR + ox;
        Py[i] = lx * sR + ly * cR + oy;
    }
#pragma unroll
    for (int i = 4; i < 8; ++i) { Px[i] = 0.f; Py[i] = 0.f; }
    int n = 4;

    const float hx = b[3] * 0.5f, hy = b[4] * 0.5f;
    clip_pass(Px, Py, n, 1.f, 0.f, hx);
    clip_pass(Px, Py, n, -1.f, 0.f, hx);
    clip_pass(Px, Py, n, 0.f, 1.f, hy);
    clip_pass(Px, Py, n, 0.f, -1.f, hy);

    float area2 = 0.f;
#pragma unroll
    for (int k = 0; k < 8; ++k) {
        if (k < n) {
            float nx, ny;
            if (k == 7) { nx = Px[0]; ny = Py[0]; }
            else if (k + 1 == n) { nx = Px[0]; ny = Py[0]; }
            else { nx = Px[k + 1]; ny = Py[k + 1]; }
            area2 += Px[k] * ny - Py[k] * nx;
        }
    }
    return 0.5f * fabsf(area2);
}

__device__ float iou3d(const float* __restrict__ a, const float* __restrict__ b) {
    const float inter_bev = bev_inter(a, b);
    const float top = fminf(a[2] + a[5] * 0.5f, b[2] + b[5] * 0.5f);
    const float bot = fmaxf(a[2] - a[5] * 0.5f, b[2] - b[5] * 0.5f);
    const float inter = inter_bev * fmaxf(top - bot, 0.f);
    const float va = a[3] * a[4] * a[5];
    const float vb = b[3] * b[4] * b[5];
    return inter / fmaxf(va + vb - inter, 1e-6f);
}

__global__ void __launch_bounds__(BLOCK)
iou_loss_pairs(const float* __restrict__ iou_pred,
               const int* __restrict__ mask,
               const int* __restrict__ ind,
               const float* __restrict__ box_pred,
               const float* __restrict__ box_gt,
               float* __restrict__ ws) {
    const int idx = blockIdx.x * BLOCK + threadIdx.x;  // always < NPAIR (exact fit)
    const int b = idx / Mc;
    const int i = ind[idx];
    const float pred = iou_pred[(size_t)b * HWc + i];

    float pb[7], gb[7];
    const float* bp = box_pred + (size_t)b * Dc * HWc + i;
#pragma unroll
    for (int d = 0; d < 7; ++d) pb[d] = bp[(size_t)d * HWc];
#pragma unroll
    for (int d = 0; d < 7; ++d) gb[d] = box_gt[(size_t)idx * 7 + d];

    const float iou = iou3d(pb, gb);
    const float target = 2.f * iou - 1.f;
    const float mm = (float)mask[idx];
    float term = fabsf(pred - target) * mm;
    float mv = mm;

    // single-wave block: pure shuffle reduction, no LDS round-trip
#pragma unroll
    for (int off = 32; off > 0; off >>= 1) {
        term += __shfl_down(term, off);
        mv += __shfl_down(mv, off);
    }
    if (threadIdx.x == 0) {
        ws[blockIdx.x] = term;
        ws[128 + blockIdx.x] = mv;
    }
}

__global__ void iou_loss_finalize(const float* __restrict__ ws, float* __restrict__ out) {
    const int t = threadIdx.x;  // 64 threads
    float s = 0.f, m = 0.f;
    for (int i = t; i < NBLK; i += 64) {
        s += ws[i];
        m += ws[128 + i];
    }
#pragma unroll
    for (int off = 32; off > 0; off >>= 1) {
        s += __shfl_down(s, off);
        m += __shfl_down(m, off);
    }
    if (t == 0) out[0] = s / (m + 1e-4f);
}

extern "C" void kernel_launch(void* const* d_in, const int* in_sizes, int n_in,
                              void* d_out, int out_size, void* d_ws, size_t ws_size,
                              hipStream_t stream) {
    const float* iou_pred = (const float*)d_in[0];
    const int* mask = (const int*)d_in[1];
    const int* ind = (const int*)d_in[2];
    const float* box_pred = (const float*)d_in[3];
    const float* box_gt = (const float*)d_in[4];
    float* ws = (float*)d_ws;
    float* out = (float*)d_out;

    iou_loss_pairs<<<NBLK, BLOCK, 0, stream>>>(iou_pred, mask, ind, box_pred, box_gt, ws);
    iou_loss_finalize<<<1, 64, 0, stream>>>(ws, out);
}